// Round 8
// baseline (135.300 us; speedup 1.0000x reference)
//
#include <hip/hip_runtime.h>

#define SEQLEN 512
#define NBATCH 256

typedef __attribute__((ext_vector_type(8))) __bf16 bf16x8;
typedef __attribute__((ext_vector_type(4))) float f32x4;
typedef unsigned short u16;
typedef unsigned int u32;

union B8 { bf16x8 v; u16 s[8]; uint4 q; };

__device__ __forceinline__ u16 rneb(float f) {   // f32 -> bf16 bits, RNE
    u32 u = __float_as_uint(f);
    return (u16)((u + 0x7FFFu + ((u >> 16) & 1u)) >> 16);
}

template <int CTRL>
__device__ __forceinline__ float dpp_add(float x) {
    int y = __builtin_amdgcn_update_dpp(0, __float_as_int(x), CTRL, 0xF, 0xF, true);
    return x + __int_as_float(y);
}
// sum across each aligned 16-lane group (pure VALU/DPP, no LDS pipe)
__device__ __forceinline__ float sum16(float x) {
    x = dpp_add<0xB1>(x);     // quad_perm [1,0,3,2]
    x = dpp_add<0x4E>(x);     // quad_perm [2,3,0,1]
    x = dpp_add<0x141>(x);    // row_half_mirror
    x = dpp_add<0x140>(x);    // row_mirror
    return x;
}

__device__ __forceinline__ float dot4(const float4& k, float u0, float u1,
                                      float u2, float u3) {
    return fmaf(k.x, u0, k.y * u1) + fmaf(k.z, u2, k.w * u3);
}

// ---------------------------------------------------------------------------
// k0: weight prep into d_ws. w1t[j][i] = bf16(w1[i][j])  (128x64);
//                            w2t[m][j] = bf16(w2[j][m])  (64x128).
// ---------------------------------------------------------------------------
__global__ __launch_bounds__(256) void k0_prep(const float* __restrict__ w1,
                                               const float* __restrict__ w2,
                                               u16* __restrict__ w1t,
                                               u16* __restrict__ w2t) {
    int t = blockIdx.x * 256 + threadIdx.x;     // 0..16383
    if (t < 8192) {
        int j = t >> 6, i = t & 63;
        w1t[t] = rneb(w1[i * 128 + j]);
    } else {
        int t2 = t - 8192;
        int m = t2 >> 7, j = t2 & 127;
        w2t[t2] = rneb(w2[j * 64 + m]);
    }
}

// LDS map (bytes):
//   Ksh : 0      .. 131072   [512][64] f32, col ^ ((row&7)<<3)
//   Ssh : 131072 .. 133120   [512] f32
//   stag: 133120 .. 149504   8 waves x 2048 B   (Phase A only)
//   Gq  : 133120 .. 137216   128 quads x 8 f32  (after Phase A barrier)
//   ysh : 137216 .. 137472 ; zsh : 137472 .. 137728

__global__ __launch_bounds__(512, 2) void fused_all(
    const int* __restrict__ seq, const float* __restrict__ embed,
    const u16* __restrict__ w1t, const float* __restrict__ b1,
    const u16* __restrict__ w2t, const float* __restrict__ b2,
    const float* __restrict__ ln_g, const float* __restrict__ ln_b,
    const float* __restrict__ rp_w, const float* __restrict__ rp_b,
    const float* __restrict__ out_w, const float* __restrict__ out_b,
    float* __restrict__ out)
{
    __shared__ __align__(16) unsigned char smem[149504];
    float* Ksh = (float*)smem;
    float* Ssh = (float*)(smem + 131072);
    u16*  t1b  = (u16*)(smem + 133120);
    float* Gq  = (float*)(smem + 133120);
    float* ysh = (float*)(smem + 137216);
    float* zsh = (float*)(smem + 137472);

    const int tid = threadIdx.x;
    const int wv  = tid >> 6;              // 0..7
    const int l   = tid & 63;
    const int g   = l >> 4;                // 0..3
    const int tl  = l & 15;
    const int b   = blockIdx.x;

    u16* myT = t1b + wv * 1024 + tl * 64;   // 2 KB per wave
    const int swz = (tl & 7) << 3;

    // ---- Phase A: MLP + LN, 4 groups of 16 tokens per wave ----
    for (int grp = 0; grp < 4; ++grp) {
        const int lt = wv * 64 + grp * 16 + tl;
        const int idx = seq[b * SEQLEN + lt];
        const float* erow = embed + idx * 64;

        B8 xb0, xb1;
        {
            float4 c0 = *reinterpret_cast<const float4*>(erow + g * 8);
            float4 c1 = *reinterpret_cast<const float4*>(erow + g * 8 + 4);
            xb0.s[0] = rneb(c0.x); xb0.s[1] = rneb(c0.y); xb0.s[2] = rneb(c0.z); xb0.s[3] = rneb(c0.w);
            xb0.s[4] = rneb(c1.x); xb0.s[5] = rneb(c1.y); xb0.s[6] = rneb(c1.z); xb0.s[7] = rneb(c1.w);
            float4 c2 = *reinterpret_cast<const float4*>(erow + 32 + g * 8);
            float4 c3 = *reinterpret_cast<const float4*>(erow + 32 + g * 8 + 4);
            xb1.s[0] = rneb(c2.x); xb1.s[1] = rneb(c2.y); xb1.s[2] = rneb(c2.z); xb1.s[3] = rneb(c2.w);
            xb1.s[4] = rneb(c3.x); xb1.s[5] = rneb(c3.y); xb1.s[6] = rneb(c3.z); xb1.s[7] = rneb(c3.w);
        }

        f32x4 acc2[4];
#pragma unroll
        for (int mt = 0; mt < 4; ++mt) acc2[mt] = (f32x4){0.f, 0.f, 0.f, 0.f};

        // two half-K passes: GEMM1 (4 ntiles) -> stage 2KB -> GEMM2 (2 ksteps)
#pragma unroll
        for (int half = 0; half < 2; ++half) {
            f32x4 acc[4];
#pragma unroll
            for (int nt = 0; nt < 4; ++nt) {
                const int NT = half * 4 + nt;
                const u16* arow = w1t + (NT * 16 + tl) * 64 + g * 8;
                B8 a0; a0.q = *reinterpret_cast<const uint4*>(arow);
                B8 a1; a1.q = *reinterpret_cast<const uint4*>(arow + 32);
                acc[nt] = (f32x4){0.f, 0.f, 0.f, 0.f};
                acc[nt] = __builtin_amdgcn_mfma_f32_16x16x32_bf16(a0.v, xb0.v, acc[nt], 0, 0, 0);
                acc[nt] = __builtin_amdgcn_mfma_f32_16x16x32_bf16(a1.v, xb1.v, acc[nt], 0, 0, 0);
            }
#pragma unroll
            for (int nt = 0; nt < 4; ++nt) {
                const int NT = half * 4 + nt;
                float4 bb = *reinterpret_cast<const float4*>(b1 + NT * 16 + g * 4);
                u32 lo = (u32)rneb(fmaxf(acc[nt][0] + bb.x, 0.f)) |
                         ((u32)rneb(fmaxf(acc[nt][1] + bb.y, 0.f)) << 16);
                u32 hi = (u32)rneb(fmaxf(acc[nt][2] + bb.z, 0.f)) |
                         ((u32)rneb(fmaxf(acc[nt][3] + bb.w, 0.f)) << 16);
                *reinterpret_cast<uint2*>(&myT[(nt * 16 + g * 4) ^ swz]) = make_uint2(lo, hi);
            }
#pragma unroll
            for (int k2l = 0; k2l < 2; ++k2l) {
                const int KK = half * 2 + k2l;
                B8 tb; tb.q = *reinterpret_cast<const uint4*>(&myT[(k2l * 32 + g * 8) ^ swz]);
#pragma unroll
                for (int mt = 0; mt < 4; ++mt) {
                    B8 wb; wb.q = *reinterpret_cast<const uint4*>(
                        w2t + (mt * 16 + tl) * 128 + KK * 32 + g * 8);
                    acc2[mt] = __builtin_amdgcn_mfma_f32_16x16x32_bf16(wb.v, tb.v, acc2[mt], 0, 0, 0);
                }
            }
        }

        // epilogue: x = ff + h + b2 ; LN ; normalize ; -> Ksh/Ssh
        float x[16];
        float sum = 0.f;
#pragma unroll
        for (int mt = 0; mt < 4; ++mt) {
            float4 hr  = *reinterpret_cast<const float4*>(erow + mt * 16 + g * 4);
            float4 b2v = *reinterpret_cast<const float4*>(b2 + mt * 16 + g * 4);
            x[4*mt+0] = acc2[mt][0] + hr.x + b2v.x;
            x[4*mt+1] = acc2[mt][1] + hr.y + b2v.y;
            x[4*mt+2] = acc2[mt][2] + hr.z + b2v.z;
            x[4*mt+3] = acc2[mt][3] + hr.w + b2v.w;
            sum += x[4*mt+0] + x[4*mt+1] + x[4*mt+2] + x[4*mt+3];
        }
        sum += __shfl_xor(sum, 16);
        sum += __shfl_xor(sum, 32);
        float mu = sum * (1.f / 64.f);

        float vs = 0.f;
#pragma unroll
        for (int i = 0; i < 16; ++i) { float d = x[i] - mu; vs = fmaf(d, d, vs); }
        vs += __shfl_xor(vs, 16);
        vs += __shfl_xor(vs, 32);
        float rstd = 1.f / sqrtf(vs * (1.f / 64.f) + 1e-5f);

        float ss = 0.f;
#pragma unroll
        for (int mt = 0; mt < 4; ++mt) {
            float4 gv = *reinterpret_cast<const float4*>(ln_g + mt * 16 + g * 4);
            float4 bv = *reinterpret_cast<const float4*>(ln_b + mt * 16 + g * 4);
            float k0 = fmaf((x[4*mt+0] - mu) * rstd, gv.x, bv.x);
            float k1 = fmaf((x[4*mt+1] - mu) * rstd, gv.y, bv.y);
            float k2 = fmaf((x[4*mt+2] - mu) * rstd, gv.z, bv.z);
            float k3 = fmaf((x[4*mt+3] - mu) * rstd, gv.w, bv.w);
            x[4*mt+0] = k0; x[4*mt+1] = k1; x[4*mt+2] = k2; x[4*mt+3] = k3;
            ss = fmaf(k0, k0, ss); ss = fmaf(k1, k1, ss);
            ss = fmaf(k2, k2, ss); ss = fmaf(k3, k3, ss);
        }
        ss += __shfl_xor(ss, 16);
        ss += __shfl_xor(ss, 32);
        float s = fmaxf(sqrtf(ss), 1e-12f);
        float rn = 1.f / s;

        const int rsw = (lt & 7) << 3;
#pragma unroll
        for (int mt = 0; mt < 4; ++mt)
            *reinterpret_cast<float4*>(Ksh + lt * 64 + ((mt * 16 + g * 4) ^ rsw)) =
                make_float4(x[4*mt+0] * rn, x[4*mt+1] * rn, x[4*mt+2] * rn, x[4*mt+3] * rn);
        if (l < 16) Ssh[lt] = s;
    }

    __syncthreads();

    // ---- Gram precompute: 128 quads x 6 pair-dots (all 8 waves) ----
    // quad q rows R=4q..4q+3; processing order a_i = kn[4q+3-i].
    // store [G10,G20,G21,G30] + [G31,G32] at Gq + q*8.
#pragma unroll
    for (int pass = 0; pass < 4; ++pass) {
        const int q = pass * 32 + wv * 4 + g;
        const int R0 = 4 * q;
        float4 r0 = *reinterpret_cast<const float4*>(Ksh + (R0+0) * 64 + ((tl*4) ^ (((R0+0)&7)<<3)));
        float4 r1 = *reinterpret_cast<const float4*>(Ksh + (R0+1) * 64 + ((tl*4) ^ (((R0+1)&7)<<3)));
        float4 r2 = *reinterpret_cast<const float4*>(Ksh + (R0+2) * 64 + ((tl*4) ^ (((R0+2)&7)<<3)));
        float4 r3 = *reinterpret_cast<const float4*>(Ksh + (R0+3) * 64 + ((tl*4) ^ (((R0+3)&7)<<3)));
        float d10 = fmaf(r2.x, r3.x, r2.y * r3.y) + fmaf(r2.z, r3.z, r2.w * r3.w);
        float d20 = fmaf(r1.x, r3.x, r1.y * r3.y) + fmaf(r1.z, r3.z, r1.w * r3.w);
        float d21 = fmaf(r1.x, r2.x, r1.y * r2.y) + fmaf(r1.z, r2.z, r1.w * r2.w);
        float d30 = fmaf(r0.x, r3.x, r0.y * r3.y) + fmaf(r0.z, r3.z, r0.w * r3.w);
        float d31 = fmaf(r0.x, r2.x, r0.y * r2.y) + fmaf(r0.z, r2.z, r0.w * r2.w);
        float d32 = fmaf(r0.x, r1.x, r0.y * r1.y) + fmaf(r0.z, r1.z, r0.w * r1.w);
        d10 = sum16(d10); d20 = sum16(d20); d21 = sum16(d21);
        d30 = sum16(d30); d31 = sum16(d31); d32 = sum16(d32);
        if (tl == 0) {
            *reinterpret_cast<float4*>(Gq + q * 8)     = make_float4(d10, d20, d21, d30);
            *reinterpret_cast<float2*>(Gq + q * 8 + 4) = make_float2(d31, d32);
        }
    }

    __syncthreads();

    // ---- Phase B: quad-blocked backward scan (wave 0), flat registers ----
#define QLOADM(X, Q_) do {                                                    \
    const int Qc = (Q_) < 0 ? 0 : (Q_);                                       \
    const int R0 = 4 * Qc;                                                    \
    X##k0 = *reinterpret_cast<const float4*>(Ksh + (R0+0)*64 + ((c4) ^ (((R0+0)&7)<<3))); \
    X##k1 = *reinterpret_cast<const float4*>(Ksh + (R0+1)*64 + ((c4) ^ (((R0+1)&7)<<3))); \
    X##k2 = *reinterpret_cast<const float4*>(Ksh + (R0+2)*64 + ((c4) ^ (((R0+2)&7)<<3))); \
    X##k3 = *reinterpret_cast<const float4*>(Ksh + (R0+3)*64 + ((c4) ^ (((R0+3)&7)<<3))); \
    X##sv = *reinterpret_cast<const float4*>(Ssh + R0);                       \
    X##g0 = *reinterpret_cast<const float4*>(Gq + Qc * 8);                    \
    X##g1 = *reinterpret_cast<const float2*>(Gq + Qc * 8 + 4);                \
} while (0)

#define QSTEPM(X) do {                                                        \
    float pp0 = dot4(X##k3, u0, u1, u2, u3);                                  \
    float pp1 = dot4(X##k2, u0, u1, u2, u3);                                  \
    float pp2 = dot4(X##k1, u0, u1, u2, u3);                                  \
    float pp3 = dot4(X##k0, u0, u1, u2, u3);                                  \
    float P0 = sum16(pp0), P1 = sum16(pp1), P2 = sum16(pp2), P3 = sum16(pp3); \
    float c0 = P0;                                                            \
    float c1 = fmaf(-X##g0.x, c0, P1);                                        \
    float c2 = fmaf(-X##g0.z, c1, fmaf(-X##g0.y, c0, P2));                    \
    float c3 = fmaf(-X##g1.y, c2, fmaf(-X##g1.x, c1, fmaf(-X##g0.w, c0, P3)));\
    u0 -= c0*X##k3.x + c1*X##k2.x + c2*X##k1.x + c3*X##k0.x;                  \
    u1 -= c0*X##k3.y + c1*X##k2.y + c2*X##k1.y + c3*X##k0.y;                  \
    u2 -= c0*X##k3.z + c1*X##k2.z + c2*X##k1.z + c3*X##k0.z;                  \
    u3 -= c0*X##k3.w + c1*X##k2.w + c2*X##k1.w + c3*X##k0.w;                  \
    float d0 = c0*X##sv.w, d1 = c1*X##sv.z, d2 = c2*X##sv.y, d3 = c3*X##sv.x; \
    y0 += d0*X##k3.x + d1*X##k2.x + d2*X##k1.x + d3*X##k0.x;                  \
    y1 += d0*X##k3.y + d1*X##k2.y + d2*X##k1.y + d3*X##k0.y;                  \
    y2 += d0*X##k3.z + d1*X##k2.z + d2*X##k1.z + d3*X##k0.z;                  \
    y3 += d0*X##k3.w + d1*X##k2.w + d2*X##k1.w + d3*X##k0.w;                  \
} while (0)

    if (wv == 0) {
        const int c4 = tl * 4;
        float u0, u1, u2, u3, y0 = 0.f, y1 = 0.f, y2 = 0.f, y3 = 0.f;
        float4 Ak0, Ak1, Ak2, Ak3, Asv, Ag0; float2 Ag1;
        float4 Bk0, Bk1, Bk2, Bk3, Bsv, Bg0; float2 Bg1;
        float4 Ck0, Ck1, Ck2, Ck3, Csv, Cg0; float2 Cg1;

        // quad 127: row 511 = query (u init), steps 510 (k2), 509 (k1), 508 (k0)
        QLOADM(A, 127);
        {
            float s511 = Asv.w;
            u0 = Ak3.x * s511; u1 = Ak3.y * s511;
            u2 = Ak3.z * s511; u3 = Ak3.w * s511;
            float pp1 = dot4(Ak2, u0, u1, u2, u3);
            float pp2 = dot4(Ak1, u0, u1, u2, u3);
            float pp3 = dot4(Ak0, u0, u1, u2, u3);
            float P1 = sum16(pp1), P2 = sum16(pp2), P3 = sum16(pp3);
            float c1 = P1;
            float c2 = fmaf(-Ag0.z, c1, P2);
            float c3 = fmaf(-Ag1.y, c2, fmaf(-Ag1.x, c1, P3));
            u0 -= c1*Ak2.x + c2*Ak1.x + c3*Ak0.x;
            u1 -= c1*Ak2.y + c2*Ak1.y + c3*Ak0.y;
            u2 -= c1*Ak2.z + c2*Ak1.z + c3*Ak0.z;
            u3 -= c1*Ak2.w + c2*Ak1.w + c3*Ak0.w;
            float d1 = c1*Asv.z, d2 = c2*Asv.y, d3 = c3*Asv.x;
            y0 += d1*Ak2.x + d2*Ak1.x + d3*Ak0.x;
            y1 += d1*Ak2.y + d2*Ak1.y + d3*Ak0.y;
            y2 += d1*Ak2.z + d2*Ak1.z + d3*Ak0.z;
            y3 += d1*Ak2.w + d2*Ak1.w + d3*Ak0.w;
        }

        // quads 126..0 with 3-bank rotation (2-quad prefetch lead)
        QLOADM(A, 126);
        QLOADM(B, 125);
        for (int c = 0; c < 42; ++c) {
            const int base = 126 - 3 * c;
            QLOADM(C, base - 2);
            QSTEPM(A);
            QLOADM(A, base - 3);
            QSTEPM(B);
            QLOADM(B, base - 4);
            QSTEPM(C);
        }
        QSTEPM(A);   // quad 0

        if (l < 16)
            *reinterpret_cast<float4*>(&ysh[tl * 4]) = make_float4(y0, y1, y2, y3);
    }

    // ---- Phase C: head (wave 0 only; LDS ordering is wave-internal) ----
    if (tid < 64) {
        float z = rp_b[tid];
#pragma unroll 8
        for (int j = 0; j < 64; ++j) z = fmaf(ysh[j], rp_w[j * 64 + tid], z);
        zsh[tid] = z;
        float o = out_b[tid];
#pragma unroll 8
        for (int j = 0; j < 64; ++j) o = fmaf(zsh[j], out_w[j * 64 + tid], o);
        out[b * 64 + tid] = o;
    }
}

// ---------------------------------------------------------------------------
extern "C" void kernel_launch(void* const* d_in, const int* in_sizes, int n_in,
                              void* d_out, int out_size, void* d_ws, size_t ws_size,
                              hipStream_t stream) {
    const int*   seq   = (const int*)d_in[0];
    const float* embed = (const float*)d_in[1];
    const float* w1    = (const float*)d_in[2];
    const float* b1    = (const float*)d_in[3];
    const float* w2    = (const float*)d_in[4];
    const float* b2    = (const float*)d_in[5];
    const float* ln_g  = (const float*)d_in[6];
    const float* ln_b  = (const float*)d_in[7];
    const float* rp_w  = (const float*)d_in[8];
    const float* rp_b  = (const float*)d_in[9];
    const float* out_w = (const float*)d_in[10];
    const float* out_b = (const float*)d_in[11];
    float* out = (float*)d_out;

    u16* w1t = (u16*)d_ws;                 // 8192 u16
    u16* w2t = w1t + 8192;                 // 8192 u16

    k0_prep<<<64, 256, 0, stream>>>(w1, w2, w1t, w2t);
    fused_all<<<NBATCH, 512, 0, stream>>>(seq, embed, w1t, b1, w2t, b2,
                                          ln_g, ln_b, rp_w, rp_b,
                                          out_w, out_b, out);
}

// Round 10
// 133.522 us; speedup vs baseline: 1.0133x; 1.0133x over previous
//
#include <hip/hip_runtime.h>

#define SEQLEN 512
#define NBATCH 256

typedef __attribute__((ext_vector_type(8))) __bf16 bf16x8;
typedef __attribute__((ext_vector_type(4))) float f32x4;
typedef unsigned short u16;
typedef unsigned int u32;

union B8 { bf16x8 v; u16 s[8]; uint4 q; };

__device__ __forceinline__ u16 rneb(float f) {   // f32 -> bf16 bits, RNE
    u32 u = __float_as_uint(f);
    return (u16)((u + 0x7FFFu + ((u >> 16) & 1u)) >> 16);
}

template <int CTRL>
__device__ __forceinline__ float dpp_add(float x) {
    int y = __builtin_amdgcn_update_dpp(0, __float_as_int(x), CTRL, 0xF, 0xF, true);
    return x + __int_as_float(y);
}
// sum across each aligned 16-lane group (pure VALU/DPP, no LDS pipe)
__device__ __forceinline__ float sum16(float x) {
    x = dpp_add<0xB1>(x);     // quad_perm [1,0,3,2]
    x = dpp_add<0x4E>(x);     // quad_perm [2,3,0,1]
    x = dpp_add<0x141>(x);    // row_half_mirror
    x = dpp_add<0x140>(x);    // row_mirror
    return x;
}

__device__ __forceinline__ float dot4(const float4& k, float u0, float u1,
                                      float u2, float u3) {
    return fmaf(k.x, u0, k.y * u1) + fmaf(k.z, u2, k.w * u3);
}

// ---------------------------------------------------------------------------
// k0: weight prep into d_ws. w1t[j][i] = bf16(w1[i][j])  (128x64);
//                            w2t[m][j] = bf16(w2[j][m])  (64x128).
// ---------------------------------------------------------------------------
__global__ __launch_bounds__(256) void k0_prep(const float* __restrict__ w1,
                                               const float* __restrict__ w2,
                                               u16* __restrict__ w1t,
                                               u16* __restrict__ w2t) {
    int t = blockIdx.x * 256 + threadIdx.x;     // 0..16383
    if (t < 8192) {
        int j = t >> 6, i = t & 63;
        w1t[t] = rneb(w1[i * 128 + j]);
    } else {
        int t2 = t - 8192;
        int m = t2 >> 7, j = t2 & 127;
        w2t[t2] = rneb(w2[j * 64 + m]);
    }
}

// LDS map (bytes):
//   Ksh : 0      .. 131072   [512][64] f32, col ^ ((row&7)<<3)
//   Ssh : 131072 .. 133120   [512] f32
//   stag: 133120 .. 149504   8 waves x 2048 B   (Phase A only)
//   Gq  : 133120 .. 137216   128 quads x 8 f32  (after Phase A barrier)
//   ysh : 137216 .. 137472 ; zsh : 137472 .. 137728

// NOTE: grid == 256 == #CUs, so only 1 block/CU can ever be resident.
// min-waves-per-EU=1 lets the allocator use up to 256 VGPRs (8-wave block
// still fits at 2 waves/SIMD) -- R8's (512,2) capped VGPRs at 128 and the
// resulting scan-loop spills were the entire 61us.
__global__ __launch_bounds__(512, 1) void fused_all(
    const int* __restrict__ seq, const float* __restrict__ embed,
    const u16* __restrict__ w1t, const float* __restrict__ b1,
    const u16* __restrict__ w2t, const float* __restrict__ b2,
    const float* __restrict__ ln_g, const float* __restrict__ ln_b,
    const float* __restrict__ rp_w, const float* __restrict__ rp_b,
    const float* __restrict__ out_w, const float* __restrict__ out_b,
    float* __restrict__ out)
{
    __shared__ __align__(16) unsigned char smem[149504];
    float* Ksh = (float*)smem;
    float* Ssh = (float*)(smem + 131072);
    u16*  t1b  = (u16*)(smem + 133120);
    float* Gq  = (float*)(smem + 133120);
    float* ysh = (float*)(smem + 137216);
    float* zsh = (float*)(smem + 137472);

    const int tid = threadIdx.x;
    const int wv  = tid >> 6;              // 0..7
    const int l   = tid & 63;
    const int g   = l >> 4;                // 0..3
    const int tl  = l & 15;
    const int b   = blockIdx.x;

    u16* myT = t1b + wv * 1024 + tl * 64;   // 2 KB per wave
    const int swz = (tl & 7) << 3;

    // ---- Phase A: MLP + LN, 4 groups of 16 tokens per wave ----
    for (int grp = 0; grp < 4; ++grp) {
        const int lt = wv * 64 + grp * 16 + tl;
        const int idx = seq[b * SEQLEN + lt];
        const float* erow = embed + idx * 64;

        B8 xb0, xb1;
        {
            float4 c0 = *reinterpret_cast<const float4*>(erow + g * 8);
            float4 c1 = *reinterpret_cast<const float4*>(erow + g * 8 + 4);
            xb0.s[0] = rneb(c0.x); xb0.s[1] = rneb(c0.y); xb0.s[2] = rneb(c0.z); xb0.s[3] = rneb(c0.w);
            xb0.s[4] = rneb(c1.x); xb0.s[5] = rneb(c1.y); xb0.s[6] = rneb(c1.z); xb0.s[7] = rneb(c1.w);
            float4 c2 = *reinterpret_cast<const float4*>(erow + 32 + g * 8);
            float4 c3 = *reinterpret_cast<const float4*>(erow + 32 + g * 8 + 4);
            xb1.s[0] = rneb(c2.x); xb1.s[1] = rneb(c2.y); xb1.s[2] = rneb(c2.z); xb1.s[3] = rneb(c2.w);
            xb1.s[4] = rneb(c3.x); xb1.s[5] = rneb(c3.y); xb1.s[6] = rneb(c3.z); xb1.s[7] = rneb(c3.w);
        }

        f32x4 acc2[4];
#pragma unroll
        for (int mt = 0; mt < 4; ++mt) acc2[mt] = (f32x4){0.f, 0.f, 0.f, 0.f};

        // two half-K passes: GEMM1 (4 ntiles) -> stage 2KB -> GEMM2 (2 ksteps)
#pragma unroll
        for (int half = 0; half < 2; ++half) {
            f32x4 acc[4];
#pragma unroll
            for (int nt = 0; nt < 4; ++nt) {
                const int NT = half * 4 + nt;
                const u16* arow = w1t + (NT * 16 + tl) * 64 + g * 8;
                B8 a0; a0.q = *reinterpret_cast<const uint4*>(arow);
                B8 a1; a1.q = *reinterpret_cast<const uint4*>(arow + 32);
                acc[nt] = (f32x4){0.f, 0.f, 0.f, 0.f};
                acc[nt] = __builtin_amdgcn_mfma_f32_16x16x32_bf16(a0.v, xb0.v, acc[nt], 0, 0, 0);
                acc[nt] = __builtin_amdgcn_mfma_f32_16x16x32_bf16(a1.v, xb1.v, acc[nt], 0, 0, 0);
            }
#pragma unroll
            for (int nt = 0; nt < 4; ++nt) {
                const int NT = half * 4 + nt;
                float4 bb = *reinterpret_cast<const float4*>(b1 + NT * 16 + g * 4);
                u32 lo = (u32)rneb(fmaxf(acc[nt][0] + bb.x, 0.f)) |
                         ((u32)rneb(fmaxf(acc[nt][1] + bb.y, 0.f)) << 16);
                u32 hi = (u32)rneb(fmaxf(acc[nt][2] + bb.z, 0.f)) |
                         ((u32)rneb(fmaxf(acc[nt][3] + bb.w, 0.f)) << 16);
                *reinterpret_cast<uint2*>(&myT[(nt * 16 + g * 4) ^ swz]) = make_uint2(lo, hi);
            }
#pragma unroll
            for (int k2l = 0; k2l < 2; ++k2l) {
                const int KK = half * 2 + k2l;
                B8 tb; tb.q = *reinterpret_cast<const uint4*>(&myT[(k2l * 32 + g * 8) ^ swz]);
#pragma unroll
                for (int mt = 0; mt < 4; ++mt) {
                    B8 wb; wb.q = *reinterpret_cast<const uint4*>(
                        w2t + (mt * 16 + tl) * 128 + KK * 32 + g * 8);
                    acc2[mt] = __builtin_amdgcn_mfma_f32_16x16x32_bf16(wb.v, tb.v, acc2[mt], 0, 0, 0);
                }
            }
        }

        // epilogue: x = ff + h + b2 ; LN ; normalize ; -> Ksh/Ssh
        float x[16];
        float sum = 0.f;
#pragma unroll
        for (int mt = 0; mt < 4; ++mt) {
            float4 hr  = *reinterpret_cast<const float4*>(erow + mt * 16 + g * 4);
            float4 b2v = *reinterpret_cast<const float4*>(b2 + mt * 16 + g * 4);
            x[4*mt+0] = acc2[mt][0] + hr.x + b2v.x;
            x[4*mt+1] = acc2[mt][1] + hr.y + b2v.y;
            x[4*mt+2] = acc2[mt][2] + hr.z + b2v.z;
            x[4*mt+3] = acc2[mt][3] + hr.w + b2v.w;
            sum += x[4*mt+0] + x[4*mt+1] + x[4*mt+2] + x[4*mt+3];
        }
        sum += __shfl_xor(sum, 16);
        sum += __shfl_xor(sum, 32);
        float mu = sum * (1.f / 64.f);

        float vs = 0.f;
#pragma unroll
        for (int i = 0; i < 16; ++i) { float d = x[i] - mu; vs = fmaf(d, d, vs); }
        vs += __shfl_xor(vs, 16);
        vs += __shfl_xor(vs, 32);
        float rstd = 1.f / sqrtf(vs * (1.f / 64.f) + 1e-5f);

        float ss = 0.f;
#pragma unroll
        for (int mt = 0; mt < 4; ++mt) {
            float4 gv = *reinterpret_cast<const float4*>(ln_g + mt * 16 + g * 4);
            float4 bv = *reinterpret_cast<const float4*>(ln_b + mt * 16 + g * 4);
            float k0 = fmaf((x[4*mt+0] - mu) * rstd, gv.x, bv.x);
            float k1 = fmaf((x[4*mt+1] - mu) * rstd, gv.y, bv.y);
            float k2 = fmaf((x[4*mt+2] - mu) * rstd, gv.z, bv.z);
            float k3 = fmaf((x[4*mt+3] - mu) * rstd, gv.w, bv.w);
            x[4*mt+0] = k0; x[4*mt+1] = k1; x[4*mt+2] = k2; x[4*mt+3] = k3;
            ss = fmaf(k0, k0, ss); ss = fmaf(k1, k1, ss);
            ss = fmaf(k2, k2, ss); ss = fmaf(k3, k3, ss);
        }
        ss += __shfl_xor(ss, 16);
        ss += __shfl_xor(ss, 32);
        float s = fmaxf(sqrtf(ss), 1e-12f);
        float rn = 1.f / s;

        const int rsw = (lt & 7) << 3;
#pragma unroll
        for (int mt = 0; mt < 4; ++mt)
            *reinterpret_cast<float4*>(Ksh + lt * 64 + ((mt * 16 + g * 4) ^ rsw)) =
                make_float4(x[4*mt+0] * rn, x[4*mt+1] * rn, x[4*mt+2] * rn, x[4*mt+3] * rn);
        if (l < 16) Ssh[lt] = s;
    }

    __syncthreads();

    // ---- Gram precompute: 128 quads x 6 pair-dots (all 8 waves) ----
    // quad q rows R=4q..4q+3; processing order a_i = kn[4q+3-i].
    // store [G10,G20,G21,G30] + [G31,G32] at Gq + q*8.
#pragma unroll
    for (int pass = 0; pass < 4; ++pass) {
        const int q = pass * 32 + wv * 4 + g;
        const int R0 = 4 * q;
        float4 r0 = *reinterpret_cast<const float4*>(Ksh + (R0+0) * 64 + ((tl*4) ^ (((R0+0)&7)<<3)));
        float4 r1 = *reinterpret_cast<const float4*>(Ksh + (R0+1) * 64 + ((tl*4) ^ (((R0+1)&7)<<3)));
        float4 r2 = *reinterpret_cast<const float4*>(Ksh + (R0+2) * 64 + ((tl*4) ^ (((R0+2)&7)<<3)));
        float4 r3 = *reinterpret_cast<const float4*>(Ksh + (R0+3) * 64 + ((tl*4) ^ (((R0+3)&7)<<3)));
        float d10 = fmaf(r2.x, r3.x, r2.y * r3.y) + fmaf(r2.z, r3.z, r2.w * r3.w);
        float d20 = fmaf(r1.x, r3.x, r1.y * r3.y) + fmaf(r1.z, r3.z, r1.w * r3.w);
        float d21 = fmaf(r1.x, r2.x, r1.y * r2.y) + fmaf(r1.z, r2.z, r1.w * r2.w);
        float d30 = fmaf(r0.x, r3.x, r0.y * r3.y) + fmaf(r0.z, r3.z, r0.w * r3.w);
        float d31 = fmaf(r0.x, r2.x, r0.y * r2.y) + fmaf(r0.z, r2.z, r0.w * r2.w);
        float d32 = fmaf(r0.x, r1.x, r0.y * r1.y) + fmaf(r0.z, r1.z, r0.w * r1.w);
        d10 = sum16(d10); d20 = sum16(d20); d21 = sum16(d21);
        d30 = sum16(d30); d31 = sum16(d31); d32 = sum16(d32);
        if (tl == 0) {
            *reinterpret_cast<float4*>(Gq + q * 8)     = make_float4(d10, d20, d21, d30);
            *reinterpret_cast<float2*>(Gq + q * 8 + 4) = make_float2(d31, d32);
        }
    }

    __syncthreads();

    // ---- Phase B: quad-blocked backward scan (wave 0), flat registers ----
#define QLOADM(X, Q_) do {                                                    \
    const int Qc = (Q_) < 0 ? 0 : (Q_);                                       \
    const int R0 = 4 * Qc;                                                    \
    X##k0 = *reinterpret_cast<const float4*>(Ksh + (R0+0)*64 + ((c4) ^ (((R0+0)&7)<<3))); \
    X##k1 = *reinterpret_cast<const float4*>(Ksh + (R0+1)*64 + ((c4) ^ (((R0+1)&7)<<3))); \
    X##k2 = *reinterpret_cast<const float4*>(Ksh + (R0+2)*64 + ((c4) ^ (((R0+2)&7)<<3))); \
    X##k3 = *reinterpret_cast<const float4*>(Ksh + (R0+3)*64 + ((c4) ^ (((R0+3)&7)<<3))); \
    X##sv = *reinterpret_cast<const float4*>(Ssh + R0);                       \
    X##g0 = *reinterpret_cast<const float4*>(Gq + Qc * 8);                    \
    X##g1 = *reinterpret_cast<const float2*>(Gq + Qc * 8 + 4);                \
} while (0)

#define QSTEPM(X) do {                                                        \
    float pp0 = dot4(X##k3, u0, u1, u2, u3);                                  \
    float pp1 = dot4(X##k2, u0, u1, u2, u3);                                  \
    float pp2 = dot4(X##k1, u0, u1, u2, u3);                                  \
    float pp3 = dot4(X##k0, u0, u1, u2, u3);                                  \
    float P0 = sum16(pp0), P1 = sum16(pp1), P2 = sum16(pp2), P3 = sum16(pp3); \
    float c0 = P0;                                                            \
    float c1 = fmaf(-X##g0.x, c0, P1);                                        \
    float c2 = fmaf(-X##g0.z, c1, fmaf(-X##g0.y, c0, P2));                    \
    float c3 = fmaf(-X##g1.y, c2, fmaf(-X##g1.x, c1, fmaf(-X##g0.w, c0, P3)));\
    u0 -= c0*X##k3.x + c1*X##k2.x + c2*X##k1.x + c3*X##k0.x;                  \
    u1 -= c0*X##k3.y + c1*X##k2.y + c2*X##k1.y + c3*X##k0.y;                  \
    u2 -= c0*X##k3.z + c1*X##k2.z + c2*X##k1.z + c3*X##k0.z;                  \
    u3 -= c0*X##k3.w + c1*X##k2.w + c2*X##k1.w + c3*X##k0.w;                  \
    float d0 = c0*X##sv.w, d1 = c1*X##sv.z, d2 = c2*X##sv.y, d3 = c3*X##sv.x; \
    y0 += d0*X##k3.x + d1*X##k2.x + d2*X##k1.x + d3*X##k0.x;                  \
    y1 += d0*X##k3.y + d1*X##k2.y + d2*X##k1.y + d3*X##k0.y;                  \
    y2 += d0*X##k3.z + d1*X##k2.z + d2*X##k1.z + d3*X##k0.z;                  \
    y3 += d0*X##k3.w + d1*X##k2.w + d2*X##k1.w + d3*X##k0.w;                  \
} while (0)

    if (wv == 0) {
        const int c4 = tl * 4;
        float u0, u1, u2, u3, y0 = 0.f, y1 = 0.f, y2 = 0.f, y3 = 0.f;
        float4 Ak0, Ak1, Ak2, Ak3, Asv, Ag0; float2 Ag1;
        float4 Bk0, Bk1, Bk2, Bk3, Bsv, Bg0; float2 Bg1;
        float4 Ck0, Ck1, Ck2, Ck3, Csv, Cg0; float2 Cg1;

        // quad 127: row 511 = query (u init), steps 510 (k2), 509 (k1), 508 (k0)
        QLOADM(A, 127);
        {
            float s511 = Asv.w;
            u0 = Ak3.x * s511; u1 = Ak3.y * s511;
            u2 = Ak3.z * s511; u3 = Ak3.w * s511;
            float pp1 = dot4(Ak2, u0, u1, u2, u3);
            float pp2 = dot4(Ak1, u0, u1, u2, u3);
            float pp3 = dot4(Ak0, u0, u1, u2, u3);
            float P1 = sum16(pp1), P2 = sum16(pp2), P3 = sum16(pp3);
            float c1 = P1;
            float c2 = fmaf(-Ag0.z, c1, P2);
            float c3 = fmaf(-Ag1.y, c2, fmaf(-Ag1.x, c1, P3));
            u0 -= c1*Ak2.x + c2*Ak1.x + c3*Ak0.x;
            u1 -= c1*Ak2.y + c2*Ak1.y + c3*Ak0.y;
            u2 -= c1*Ak2.z + c2*Ak1.z + c3*Ak0.z;
            u3 -= c1*Ak2.w + c2*Ak1.w + c3*Ak0.w;
            float d1 = c1*Asv.z, d2 = c2*Asv.y, d3 = c3*Asv.x;
            y0 += d1*Ak2.x + d2*Ak1.x + d3*Ak0.x;
            y1 += d1*Ak2.y + d2*Ak1.y + d3*Ak0.y;
            y2 += d1*Ak2.z + d2*Ak1.z + d3*Ak0.z;
            y3 += d1*Ak2.w + d2*Ak1.w + d3*Ak0.w;
        }

        // quads 126..0 with 3-bank rotation (2-quad prefetch lead)
        QLOADM(A, 126);
        QLOADM(B, 125);
        for (int c = 0; c < 42; ++c) {
            const int base = 126 - 3 * c;
            QLOADM(C, base - 2);
            QSTEPM(A);
            QLOADM(A, base - 3);
            QSTEPM(B);
            QLOADM(B, base - 4);
            QSTEPM(C);
        }
        QSTEPM(A);   // quad 0

        if (l < 16)
            *reinterpret_cast<float4*>(&ysh[tl * 4]) = make_float4(y0, y1, y2, y3);
    }

    // ---- Phase C: head (wave 0 only; LDS ordering is wave-internal) ----
    if (tid < 64) {
        float z = rp_b[tid];
#pragma unroll 8
        for (int j = 0; j < 64; ++j) z = fmaf(ysh[j], rp_w[j * 64 + tid], z);
        zsh[tid] = z;
        float o = out_b[tid];
#pragma unroll 8
        for (int j = 0; j < 64; ++j) o = fmaf(zsh[j], out_w[j * 64 + tid], o);
        out[b * 64 + tid] = o;
    }
}

// ---------------------------------------------------------------------------
extern "C" void kernel_launch(void* const* d_in, const int* in_sizes, int n_in,
                              void* d_out, int out_size, void* d_ws, size_t ws_size,
                              hipStream_t stream) {
    const int*   seq   = (const int*)d_in[0];
    const float* embed = (const float*)d_in[1];
    const float* w1    = (const float*)d_in[2];
    const float* b1    = (const float*)d_in[3];
    const float* w2    = (const float*)d_in[4];
    const float* b2    = (const float*)d_in[5];
    const float* ln_g  = (const float*)d_in[6];
    const float* ln_b  = (const float*)d_in[7];
    const float* rp_w  = (const float*)d_in[8];
    const float* rp_b  = (const float*)d_in[9];
    const float* out_w = (const float*)d_in[10];
    const float* out_b = (const float*)d_in[11];
    float* out = (float*)d_out;

    u16* w1t = (u16*)d_ws;                 // 8192 u16
    u16* w2t = w1t + 8192;                 // 8192 u16

    k0_prep<<<64, 256, 0, stream>>>(w1, w2, w1t, w2t);
    fused_all<<<NBATCH, 512, 0, stream>>>(seq, embed, w1t, b1, w2t, b2,
                                          ln_g, ln_b, rp_w, rp_b,
                                          out_w, out_b, out);
}

// Round 11
// 129.744 us; speedup vs baseline: 1.0428x; 1.0291x over previous
//
#include <hip/hip_runtime.h>

#define SEQLEN 512
#define NBATCH 256

typedef __attribute__((ext_vector_type(8))) __bf16 bf16x8;
typedef __attribute__((ext_vector_type(4))) float f32x4;
typedef unsigned short u16;
typedef unsigned int u32;

union B8 { bf16x8 v; u16 s[8]; uint4 q; };

__device__ __forceinline__ u16 rneb(float f) {   // f32 -> bf16 bits, RNE
    u32 u = __float_as_uint(f);
    return (u16)((u + 0x7FFFu + ((u >> 16) & 1u)) >> 16);
}

template <int CTRL>
__device__ __forceinline__ float dpp_add(float x) {
    int y = __builtin_amdgcn_update_dpp(0, __float_as_int(x), CTRL, 0xF, 0xF, true);
    return x + __int_as_float(y);
}
// sum across each aligned 16-lane group (pure VALU/DPP, no LDS pipe)
__device__ __forceinline__ float sum16(float x) {
    x = dpp_add<0xB1>(x);     // quad_perm [1,0,3,2]
    x = dpp_add<0x4E>(x);     // quad_perm [2,3,0,1]
    x = dpp_add<0x141>(x);    // row_half_mirror
    x = dpp_add<0x140>(x);    // row_mirror
    return x;
}

__device__ __forceinline__ float dot4(const float4& k, float u0, float u1,
                                      float u2, float u3) {
    return fmaf(k.x, u0, k.y * u1) + fmaf(k.z, u2, k.w * u3);
}

// ---------------------------------------------------------------------------
// k0: weight prep into d_ws. w1t[j][i] = bf16(w1[i][j])  (128x64);
//                            w2t[m][j] = bf16(w2[j][m])  (64x128).
// ---------------------------------------------------------------------------
__global__ __launch_bounds__(256) void k0_prep(const float* __restrict__ w1,
                                               const float* __restrict__ w2,
                                               u16* __restrict__ w1t,
                                               u16* __restrict__ w2t) {
    int t = blockIdx.x * 256 + threadIdx.x;     // 0..16383
    if (t < 8192) {
        int j = t >> 6, i = t & 63;
        w1t[t] = rneb(w1[i * 128 + j]);
    } else {
        int t2 = t - 8192;
        int m = t2 >> 7, j = t2 & 127;
        w2t[t2] = rneb(w2[j * 64 + m]);
    }
}

// LDS map (bytes):
//   Ksh : 0      .. 131072   [512][64] f32, col ^ ((row&7)<<3)
//   Ssh : 131072 .. 133120   [512] f32
//   stag: 133120 .. 149504   8 waves x 2048 B   (Phase A only)
//   Gq  : 133120 .. 137216   128 quads x 8 f32  (after Phase A barrier)
//   ysh : 137216 .. 137472 ; zsh : 137472 .. 137728

// R10 post-mortem: __launch_bounds__(512,{1,2}) both produced VGPR=128 +
// 6 MB scratch spills (bit-identical counters) -- hipcc's allocator pins
// 4 waves/SIMD for 512-thread blocks on its own heuristic. Explicit clang
// attrs: waves_per_eu(1,2) raises the VGPR budget and tells the scheduler
// the REAL occupancy (149.5 KB LDS => 1 block/CU => 2 waves/SIMD).
__global__
__attribute__((amdgpu_flat_work_group_size(512, 512)))
__attribute__((amdgpu_waves_per_eu(1, 2)))
void fused_all(
    const int* __restrict__ seq, const float* __restrict__ embed,
    const u16* __restrict__ w1t, const float* __restrict__ b1,
    const u16* __restrict__ w2t, const float* __restrict__ b2,
    const float* __restrict__ ln_g, const float* __restrict__ ln_b,
    const float* __restrict__ rp_w, const float* __restrict__ rp_b,
    const float* __restrict__ out_w, const float* __restrict__ out_b,
    float* __restrict__ out)
{
    __shared__ __align__(16) unsigned char smem[149504];
    float* Ksh = (float*)smem;
    float* Ssh = (float*)(smem + 131072);
    u16*  t1b  = (u16*)(smem + 133120);
    float* Gq  = (float*)(smem + 133120);
    float* ysh = (float*)(smem + 137216);
    float* zsh = (float*)(smem + 137472);

    const int tid = threadIdx.x;
    const int wv  = tid >> 6;              // 0..7
    const int l   = tid & 63;
    const int g   = l >> 4;                // 0..3
    const int tl  = l & 15;
    const int b   = blockIdx.x;

    u16* myT = t1b + wv * 1024 + tl * 64;   // 2 KB per wave
    const int swz = (tl & 7) << 3;

    // ---- Phase A: MLP + LN, 4 groups of 16 tokens per wave ----
    for (int grp = 0; grp < 4; ++grp) {
        const int lt = wv * 64 + grp * 16 + tl;
        const int idx = seq[b * SEQLEN + lt];
        const float* erow = embed + idx * 64;

        B8 xb0, xb1;
        {
            float4 c0 = *reinterpret_cast<const float4*>(erow + g * 8);
            float4 c1 = *reinterpret_cast<const float4*>(erow + g * 8 + 4);
            xb0.s[0] = rneb(c0.x); xb0.s[1] = rneb(c0.y); xb0.s[2] = rneb(c0.z); xb0.s[3] = rneb(c0.w);
            xb0.s[4] = rneb(c1.x); xb0.s[5] = rneb(c1.y); xb0.s[6] = rneb(c1.z); xb0.s[7] = rneb(c1.w);
            float4 c2 = *reinterpret_cast<const float4*>(erow + 32 + g * 8);
            float4 c3 = *reinterpret_cast<const float4*>(erow + 32 + g * 8 + 4);
            xb1.s[0] = rneb(c2.x); xb1.s[1] = rneb(c2.y); xb1.s[2] = rneb(c2.z); xb1.s[3] = rneb(c2.w);
            xb1.s[4] = rneb(c3.x); xb1.s[5] = rneb(c3.y); xb1.s[6] = rneb(c3.z); xb1.s[7] = rneb(c3.w);
        }

        f32x4 acc2[4];
#pragma unroll
        for (int mt = 0; mt < 4; ++mt) acc2[mt] = (f32x4){0.f, 0.f, 0.f, 0.f};

        // two half-K passes: GEMM1 (4 ntiles) -> stage 2KB -> GEMM2 (2 ksteps)
#pragma unroll
        for (int half = 0; half < 2; ++half) {
            f32x4 acc[4];
#pragma unroll
            for (int nt = 0; nt < 4; ++nt) {
                const int NT = half * 4 + nt;
                const u16* arow = w1t + (NT * 16 + tl) * 64 + g * 8;
                B8 a0; a0.q = *reinterpret_cast<const uint4*>(arow);
                B8 a1; a1.q = *reinterpret_cast<const uint4*>(arow + 32);
                acc[nt] = (f32x4){0.f, 0.f, 0.f, 0.f};
                acc[nt] = __builtin_amdgcn_mfma_f32_16x16x32_bf16(a0.v, xb0.v, acc[nt], 0, 0, 0);
                acc[nt] = __builtin_amdgcn_mfma_f32_16x16x32_bf16(a1.v, xb1.v, acc[nt], 0, 0, 0);
            }
#pragma unroll
            for (int nt = 0; nt < 4; ++nt) {
                const int NT = half * 4 + nt;
                float4 bb = *reinterpret_cast<const float4*>(b1 + NT * 16 + g * 4);
                u32 lo = (u32)rneb(fmaxf(acc[nt][0] + bb.x, 0.f)) |
                         ((u32)rneb(fmaxf(acc[nt][1] + bb.y, 0.f)) << 16);
                u32 hi = (u32)rneb(fmaxf(acc[nt][2] + bb.z, 0.f)) |
                         ((u32)rneb(fmaxf(acc[nt][3] + bb.w, 0.f)) << 16);
                *reinterpret_cast<uint2*>(&myT[(nt * 16 + g * 4) ^ swz]) = make_uint2(lo, hi);
            }
#pragma unroll
            for (int k2l = 0; k2l < 2; ++k2l) {
                const int KK = half * 2 + k2l;
                B8 tb; tb.q = *reinterpret_cast<const uint4*>(&myT[(k2l * 32 + g * 8) ^ swz]);
#pragma unroll
                for (int mt = 0; mt < 4; ++mt) {
                    B8 wb; wb.q = *reinterpret_cast<const uint4*>(
                        w2t + (mt * 16 + tl) * 128 + KK * 32 + g * 8);
                    acc2[mt] = __builtin_amdgcn_mfma_f32_16x16x32_bf16(wb.v, tb.v, acc2[mt], 0, 0, 0);
                }
            }
        }

        // epilogue: x = ff + h + b2 ; LN ; normalize ; -> Ksh/Ssh
        float x[16];
        float sum = 0.f;
#pragma unroll
        for (int mt = 0; mt < 4; ++mt) {
            float4 hr  = *reinterpret_cast<const float4*>(erow + mt * 16 + g * 4);
            float4 b2v = *reinterpret_cast<const float4*>(b2 + mt * 16 + g * 4);
            x[4*mt+0] = acc2[mt][0] + hr.x + b2v.x;
            x[4*mt+1] = acc2[mt][1] + hr.y + b2v.y;
            x[4*mt+2] = acc2[mt][2] + hr.z + b2v.z;
            x[4*mt+3] = acc2[mt][3] + hr.w + b2v.w;
            sum += x[4*mt+0] + x[4*mt+1] + x[4*mt+2] + x[4*mt+3];
        }
        sum += __shfl_xor(sum, 16);
        sum += __shfl_xor(sum, 32);
        float mu = sum * (1.f / 64.f);

        float vs = 0.f;
#pragma unroll
        for (int i = 0; i < 16; ++i) { float d = x[i] - mu; vs = fmaf(d, d, vs); }
        vs += __shfl_xor(vs, 16);
        vs += __shfl_xor(vs, 32);
        float rstd = 1.f / sqrtf(vs * (1.f / 64.f) + 1e-5f);

        float ss = 0.f;
#pragma unroll
        for (int mt = 0; mt < 4; ++mt) {
            float4 gv = *reinterpret_cast<const float4*>(ln_g + mt * 16 + g * 4);
            float4 bv = *reinterpret_cast<const float4*>(ln_b + mt * 16 + g * 4);
            float k0 = fmaf((x[4*mt+0] - mu) * rstd, gv.x, bv.x);
            float k1 = fmaf((x[4*mt+1] - mu) * rstd, gv.y, bv.y);
            float k2 = fmaf((x[4*mt+2] - mu) * rstd, gv.z, bv.z);
            float k3 = fmaf((x[4*mt+3] - mu) * rstd, gv.w, bv.w);
            x[4*mt+0] = k0; x[4*mt+1] = k1; x[4*mt+2] = k2; x[4*mt+3] = k3;
            ss = fmaf(k0, k0, ss); ss = fmaf(k1, k1, ss);
            ss = fmaf(k2, k2, ss); ss = fmaf(k3, k3, ss);
        }
        ss += __shfl_xor(ss, 16);
        ss += __shfl_xor(ss, 32);
        float s = fmaxf(sqrtf(ss), 1e-12f);
        float rn = 1.f / s;

        const int rsw = (lt & 7) << 3;
#pragma unroll
        for (int mt = 0; mt < 4; ++mt)
            *reinterpret_cast<float4*>(Ksh + lt * 64 + ((mt * 16 + g * 4) ^ rsw)) =
                make_float4(x[4*mt+0] * rn, x[4*mt+1] * rn, x[4*mt+2] * rn, x[4*mt+3] * rn);
        if (l < 16) Ssh[lt] = s;
    }

    __syncthreads();

    // ---- Gram precompute: 128 quads x 6 pair-dots (all 8 waves) ----
    // quad q rows R=4q..4q+3; processing order a_i = kn[4q+3-i].
    // store [G10,G20,G21,G30] + [G31,G32] at Gq + q*8.
#pragma unroll
    for (int pass = 0; pass < 4; ++pass) {
        const int q = pass * 32 + wv * 4 + g;
        const int R0 = 4 * q;
        float4 r0 = *reinterpret_cast<const float4*>(Ksh + (R0+0) * 64 + ((tl*4) ^ (((R0+0)&7)<<3)));
        float4 r1 = *reinterpret_cast<const float4*>(Ksh + (R0+1) * 64 + ((tl*4) ^ (((R0+1)&7)<<3)));
        float4 r2 = *reinterpret_cast<const float4*>(Ksh + (R0+2) * 64 + ((tl*4) ^ (((R0+2)&7)<<3)));
        float4 r3 = *reinterpret_cast<const float4*>(Ksh + (R0+3) * 64 + ((tl*4) ^ (((R0+3)&7)<<3)));
        float d10 = fmaf(r2.x, r3.x, r2.y * r3.y) + fmaf(r2.z, r3.z, r2.w * r3.w);
        float d20 = fmaf(r1.x, r3.x, r1.y * r3.y) + fmaf(r1.z, r3.z, r1.w * r3.w);
        float d21 = fmaf(r1.x, r2.x, r1.y * r2.y) + fmaf(r1.z, r2.z, r1.w * r2.w);
        float d30 = fmaf(r0.x, r3.x, r0.y * r3.y) + fmaf(r0.z, r3.z, r0.w * r3.w);
        float d31 = fmaf(r0.x, r2.x, r0.y * r2.y) + fmaf(r0.z, r2.z, r0.w * r2.w);
        float d32 = fmaf(r0.x, r1.x, r0.y * r1.y) + fmaf(r0.z, r1.z, r0.w * r1.w);
        d10 = sum16(d10); d20 = sum16(d20); d21 = sum16(d21);
        d30 = sum16(d30); d31 = sum16(d31); d32 = sum16(d32);
        if (tl == 0) {
            *reinterpret_cast<float4*>(Gq + q * 8)     = make_float4(d10, d20, d21, d30);
            *reinterpret_cast<float2*>(Gq + q * 8 + 4) = make_float2(d31, d32);
        }
    }

    __syncthreads();

    // ---- Phase B: quad-blocked backward scan (wave 0), 2-bank rotation ----
#define QLOADM(X, Q_) do {                                                    \
    const int Qc = (Q_) < 0 ? 0 : (Q_);                                       \
    const int R0 = 4 * Qc;                                                    \
    X##k0 = *reinterpret_cast<const float4*>(Ksh + (R0+0)*64 + ((c4) ^ (((R0+0)&7)<<3))); \
    X##k1 = *reinterpret_cast<const float4*>(Ksh + (R0+1)*64 + ((c4) ^ (((R0+1)&7)<<3))); \
    X##k2 = *reinterpret_cast<const float4*>(Ksh + (R0+2)*64 + ((c4) ^ (((R0+2)&7)<<3))); \
    X##k3 = *reinterpret_cast<const float4*>(Ksh + (R0+3)*64 + ((c4) ^ (((R0+3)&7)<<3))); \
    X##sv = *reinterpret_cast<const float4*>(Ssh + R0);                       \
    X##g0 = *reinterpret_cast<const float4*>(Gq + Qc * 8);                    \
    X##g1 = *reinterpret_cast<const float2*>(Gq + Qc * 8 + 4);                \
} while (0)

#define QSTEPM(X) do {                                                        \
    float pp0 = dot4(X##k3, u0, u1, u2, u3);                                  \
    float pp1 = dot4(X##k2, u0, u1, u2, u3);                                  \
    float pp2 = dot4(X##k1, u0, u1, u2, u3);                                  \
    float pp3 = dot4(X##k0, u0, u1, u2, u3);                                  \
    float P0 = sum16(pp0), P1 = sum16(pp1), P2 = sum16(pp2), P3 = sum16(pp3); \
    float c0 = P0;                                                            \
    float c1 = fmaf(-X##g0.x, c0, P1);                                        \
    float c2 = fmaf(-X##g0.z, c1, fmaf(-X##g0.y, c0, P2));                    \
    float c3 = fmaf(-X##g1.y, c2, fmaf(-X##g1.x, c1, fmaf(-X##g0.w, c0, P3)));\
    u0 -= c0*X##k3.x + c1*X##k2.x + c2*X##k1.x + c3*X##k0.x;                  \
    u1 -= c0*X##k3.y + c1*X##k2.y + c2*X##k1.y + c3*X##k0.y;                  \
    u2 -= c0*X##k3.z + c1*X##k2.z + c2*X##k1.z + c3*X##k0.z;                  \
    u3 -= c0*X##k3.w + c1*X##k2.w + c2*X##k1.w + c3*X##k0.w;                  \
    float d0 = c0*X##sv.w, d1 = c1*X##sv.z, d2 = c2*X##sv.y, d3 = c3*X##sv.x; \
    y0 += d0*X##k3.x + d1*X##k2.x + d2*X##k1.x + d3*X##k0.x;                  \
    y1 += d0*X##k3.y + d1*X##k2.y + d2*X##k1.y + d3*X##k0.y;                  \
    y2 += d0*X##k3.z + d1*X##k2.z + d2*X##k1.z + d3*X##k0.z;                  \
    y3 += d0*X##k3.w + d1*X##k2.w + d2*X##k1.w + d3*X##k0.w;                  \
} while (0)

    if (wv == 0) {
        const int c4 = tl * 4;
        float u0, u1, u2, u3, y0 = 0.f, y1 = 0.f, y2 = 0.f, y3 = 0.f;
        float4 Ak0, Ak1, Ak2, Ak3, Asv, Ag0; float2 Ag1;
        float4 Bk0, Bk1, Bk2, Bk3, Bsv, Bg0; float2 Bg1;

        // quad 127: row 511 = query (u init), steps 510 (k2), 509 (k1), 508 (k0)
        QLOADM(A, 127);
        {
            float s511 = Asv.w;
            u0 = Ak3.x * s511; u1 = Ak3.y * s511;
            u2 = Ak3.z * s511; u3 = Ak3.w * s511;
            float pp1 = dot4(Ak2, u0, u1, u2, u3);
            float pp2 = dot4(Ak1, u0, u1, u2, u3);
            float pp3 = dot4(Ak0, u0, u1, u2, u3);
            float P1 = sum16(pp1), P2 = sum16(pp2), P3 = sum16(pp3);
            float c1 = P1;
            float c2 = fmaf(-Ag0.z, c1, P2);
            float c3 = fmaf(-Ag1.y, c2, fmaf(-Ag1.x, c1, P3));
            u0 -= c1*Ak2.x + c2*Ak1.x + c3*Ak0.x;
            u1 -= c1*Ak2.y + c2*Ak1.y + c3*Ak0.y;
            u2 -= c1*Ak2.z + c2*Ak1.z + c3*Ak0.z;
            u3 -= c1*Ak2.w + c2*Ak1.w + c3*Ak0.w;
            float d1 = c1*Asv.z, d2 = c2*Asv.y, d3 = c3*Asv.x;
            y0 += d1*Ak2.x + d2*Ak1.x + d3*Ak0.x;
            y1 += d1*Ak2.y + d2*Ak1.y + d3*Ak0.y;
            y2 += d1*Ak2.z + d2*Ak1.z + d3*Ak0.z;
            y3 += d1*Ak2.w + d2*Ak1.w + d3*Ak0.w;
        }

        // quads 126..0, 2-bank rotation (1-2 quad prefetch lead; Ksh is LDS)
        QLOADM(A, 126);
        QLOADM(B, 125);
        for (int c = 0; c < 62; ++c) {
            const int base = 126 - 2 * c;
            QSTEPM(A);
            QLOADM(A, base - 2);
            QSTEPM(B);
            QLOADM(B, base - 3);
        }
        QSTEPM(A);          // quad 2
        QLOADM(A, 0);
        QSTEPM(B);          // quad 1
        QSTEPM(A);          // quad 0

        if (l < 16)
            *reinterpret_cast<float4*>(&ysh[tl * 4]) = make_float4(y0, y1, y2, y3);
    }

    // ---- Phase C: head (wave 0 only; LDS ordering is wave-internal) ----
    if (tid < 64) {
        float z = rp_b[tid];
#pragma unroll 8
        for (int j = 0; j < 64; ++j) z = fmaf(ysh[j], rp_w[j * 64 + tid], z);
        zsh[tid] = z;
        float o = out_b[tid];
#pragma unroll 8
        for (int j = 0; j < 64; ++j) o = fmaf(zsh[j], out_w[j * 64 + tid], o);
        out[b * 64 + tid] = o;
    }
}

// ---------------------------------------------------------------------------
extern "C" void kernel_launch(void* const* d_in, const int* in_sizes, int n_in,
                              void* d_out, int out_size, void* d_ws, size_t ws_size,
                              hipStream_t stream) {
    const int*   seq   = (const int*)d_in[0];
    const float* embed = (const float*)d_in[1];
    const float* w1    = (const float*)d_in[2];
    const float* b1    = (const float*)d_in[3];
    const float* w2    = (const float*)d_in[4];
    const float* b2    = (const float*)d_in[5];
    const float* ln_g  = (const float*)d_in[6];
    const float* ln_b  = (const float*)d_in[7];
    const float* rp_w  = (const float*)d_in[8];
    const float* rp_b  = (const float*)d_in[9];
    const float* out_w = (const float*)d_in[10];
    const float* out_b = (const float*)d_in[11];
    float* out = (float*)d_out;

    u16* w1t = (u16*)d_ws;                 // 8192 u16
    u16* w2t = w1t + 8192;                 // 8192 u16

    k0_prep<<<64, 256, 0, stream>>>(w1, w2, w1t, w2t);
    fused_all<<<NBATCH, 512, 0, stream>>>(seq, embed, w1t, b1, w2t, b2,
                                          ln_g, ln_b, rp_w, rp_b,
                                          out_w, out_b, out);
}